// Round 1
// baseline (243.966 us; speedup 1.0000x reference)
//
#include <hip/hip_runtime.h>
#include <math.h>

// ---------------- problem constants ----------------
#define NB        512
#define ND        32
#define NCOND     30
#define NS        21                  // NB_STEPS+1 quadrature nodes
#define NBD       (NB*ND)             // 16384
#define NROWS     (NBD*NS)            // 344064 MLP evaluations
#define MBLK      64                  // rows per block
#define NBLOCKS   (NROWS/MBLK)        // 5376

// packed-weight element counts (ushort): W0 1 ktile, W1/W2 8 ktiles, 16 coltiles
#define W0P_ELEMS (1*16*64*8)         // 8192
#define W1P_ELEMS (8*16*64*8)         // 65536
#define WP_TOTAL  (W0P_ELEMS + 2*W1P_ELEMS)  // 139264

typedef __bf16 bf8 __attribute__((ext_vector_type(8)));
typedef float  fx4 __attribute__((ext_vector_type(4)));
typedef unsigned short us8 __attribute__((ext_vector_type(8)));

__device__ __forceinline__ unsigned short f2bf(float f) {
  unsigned int u = __float_as_uint(f);
  u += 0x7FFFu + ((u >> 16) & 1u);        // round-to-nearest-even
  return (unsigned short)(u >> 16);
}
__device__ __forceinline__ float bf2f(unsigned short b) {
  return __uint_as_float(((unsigned int)b) << 16);
}

// ---------------- kernel 1: pack weights to bf16 MFMA B-fragment order ----------
// packed index p = ((kt*16+ct)*64+lane)*8 + i ; source W[k][j], k=kt*32+(lane>>4)*8+i,
// j = ct*16 + (lane&15). K padded with zeros (W0: 31->32).
__global__ void prep_pack(const float* __restrict__ W0,
                          const float* __restrict__ W1,
                          const float* __restrict__ W2,
                          unsigned short* __restrict__ wp) {
  int t = blockIdx.x * blockDim.x + threadIdx.x;   // one thread = one 8-elem frag
  if (t >= WP_TOTAL / 8) return;
  int base = t * 8;
  const float* W;
  int rem, K;
  if (base < W0P_ELEMS)                      { W = W0; rem = base;                 K = 31;  }
  else if (base < W0P_ELEMS + W1P_ELEMS)     { W = W1; rem = base - W0P_ELEMS;     K = 256; }
  else                                       { W = W2; rem = base - W0P_ELEMS - W1P_ELEMS; K = 256; }
  int lane = (rem >> 3) & 63;
  int ct   = (rem >> 9) & 15;
  int ktl  =  rem >> 13;
  int j  = ct * 16 + (lane & 15);
  int k0 = ktl * 32 + (lane >> 4) * 8;
  us8 out;
#pragma unroll
  for (int i = 0; i < 8; ++i) {
    int k = k0 + i;
    float v = (k < K) ? W[k * 256 + j] : 0.0f;
    out[i] = f2bf(v);
  }
  *reinterpret_cast<us8*>(wp + base) = out;
}

// ---------------- fused MLP kernel ----------------
// 4 waves/block; wave owns 16 rows; activations [64][256] bf16 in LDS,
// byte-swizzle off ^= (row&7)<<4 to kill ds_read_b128 bank conflicts.
__device__ __forceinline__ bf8 lds_afrag(const unsigned char* src, int wave, int lane, int kt) {
  int row = wave * 16 + (lane & 15);
  unsigned int off = (unsigned int)(row * 512 + kt * 64 + (lane >> 4) * 16);
  off ^= (unsigned int)((row & 7) << 4);
  return *reinterpret_cast<const bf8*>(src + off);
}

__device__ __forceinline__ void act_store(unsigned char* dst, int wave, int lane,
                                          const fx4* acc, const float* bias) {
  int colb  = lane & 15;
  int khalf = lane >> 4;
#pragma unroll
  for (int ct = 0; ct < 16; ++ct) {
    int col = ct * 16 + colb;
    float bv = bias[col];
#pragma unroll
    for (int reg = 0; reg < 4; ++reg) {
      int row = wave * 16 + khalf * 4 + reg;           // C layout: row=(lane>>4)*4+reg
      float v = fmaxf(acc[ct][reg] + bv, 0.0f);        // ReLU
      unsigned int off = (unsigned int)(row * 512 + col * 2);
      off ^= (unsigned int)((row & 7) << 4);
      *reinterpret_cast<unsigned short*>(dst + off) = f2bf(v);
    }
  }
}

__global__ __launch_bounds__(256, 2)
void mlp_kernel(const float* __restrict__ x, const float* __restrict__ h,
                const float* __restrict__ b0, const float* __restrict__ b1,
                const float* __restrict__ b2, const float* __restrict__ W3,
                const float* __restrict__ b3,
                const unsigned short* __restrict__ wp,
                float* __restrict__ fbuf) {
  __shared__ __align__(16) unsigned char ldsA[64 * 512];
  __shared__ __align__(16) unsigned char ldsB[64 * 512];
  __shared__ float cst[1024];                       // b0|b1|b2|W3
  int tid = threadIdx.x;
  cst[tid]       = b0[tid];
  cst[256 + tid] = b1[tid];
  cst[512 + tid] = b2[tid];
  cst[768 + tid] = W3[tid];
  __syncthreads();

  int wave = tid >> 6, lane = tid & 63;
  int rowt  = lane & 15;
  int khalf = lane >> 4;
  int r = blockIdx.x * MBLK + wave * 16 + rowt;     // global MLP-eval row
  unsigned int bd = (unsigned int)r / NS;
  int s = r - (int)bd * NS;

  // ---- build input A-fragment in registers (no LDS needed for layer 0) ----
  float xv = x[bd];
  float node = xv * (cosf((float)s * 0.15707963267948966f) + 1.0f) * 0.5f;
  int k0 = khalf * 8;
  us8 au;
#pragma unroll
  for (int i = 0; i < 8; ++i) {
    int c = k0 + i;
    float v;
    if (c == 0)       v = node;
    else if (c <= 30) v = h[bd * NCOND + (c - 1)];
    else              v = 0.0f;
    au[i] = f2bf(v);
  }
  bf8 afrag = __builtin_bit_cast(bf8, au);

  fx4 acc[16];
  // ---- layer 0: K=32 (one MFMA K-step), 16 col-tiles ----
#pragma unroll
  for (int ct = 0; ct < 16; ++ct) {
    bf8 bf = *reinterpret_cast<const bf8*>(wp + (ct * 64 + lane) * 8);
    fx4 z = {0.f, 0.f, 0.f, 0.f};
    acc[ct] = __builtin_amdgcn_mfma_f32_16x16x32_bf16(afrag, bf, z, 0, 0, 0);
  }
  act_store(ldsA, wave, lane, acc, cst + 0);

  // ---- layers 1 & 2: 256->256, K=256 = 8 K-steps ----
  const unsigned short* wb1 = wp + W0P_ELEMS;
  const unsigned short* wb2 = wp + W0P_ELEMS + W1P_ELEMS;
  {
#pragma unroll
    for (int ct = 0; ct < 16; ++ct) acc[ct] = fx4{0.f, 0.f, 0.f, 0.f};
#pragma unroll
    for (int kt = 0; kt < 8; ++kt) {
      bf8 a = lds_afrag(ldsA, wave, lane, kt);
      const unsigned short* wk = wb1 + (kt * 16 * 64) * 8;
#pragma unroll
      for (int ct = 0; ct < 16; ++ct) {
        bf8 bf = *reinterpret_cast<const bf8*>(wk + (ct * 64 + lane) * 8);
        acc[ct] = __builtin_amdgcn_mfma_f32_16x16x32_bf16(a, bf, acc[ct], 0, 0, 0);
      }
    }
    act_store(ldsB, wave, lane, acc, cst + 256);
  }
  {
#pragma unroll
    for (int ct = 0; ct < 16; ++ct) acc[ct] = fx4{0.f, 0.f, 0.f, 0.f};
#pragma unroll
    for (int kt = 0; kt < 8; ++kt) {
      bf8 a = lds_afrag(ldsB, wave, lane, kt);
      const unsigned short* wk = wb2 + (kt * 16 * 64) * 8;
#pragma unroll
      for (int ct = 0; ct < 16; ++ct) {
        bf8 bf = *reinterpret_cast<const bf8*>(wk + (ct * 64 + lane) * 8);
        acc[ct] = __builtin_amdgcn_mfma_f32_16x16x32_bf16(a, bf, acc[ct], 0, 0, 0);
      }
    }
    act_store(ldsA, wave, lane, acc, cst + 512);
  }

  // ---- layer 3: 256 -> 1 dot product (VALU), ELU(y)+1 ----
  int row3 = lane >> 2;          // 0..15 within wave tile
  int sub  = lane & 3;           // 4 lanes share one row, 64 cols each
  int grow = wave * 16 + row3;
  float sum = 0.f;
#pragma unroll
  for (int jj = 0; jj < 8; ++jj) {
    int cbase = sub * 64 + jj * 8;
    unsigned int off = (unsigned int)(grow * 512 + cbase * 2);
    off ^= (unsigned int)((grow & 7) << 4);
    us8 av = *reinterpret_cast<const us8*>(ldsA + off);
#pragma unroll
    for (int ii = 0; ii < 8; ++ii)
      sum += bf2f(av[ii]) * cst[768 + cbase + ii];
  }
  sum += __shfl_down(sum, 2);
  sum += __shfl_down(sum, 1);
  if (sub == 0) {
    float y = sum + b3[0];
    float f = (y > 0.f) ? (y + 1.f) : expf(y);     // elu(y)+1
    fbuf[blockIdx.x * MBLK + wave * 16 + row3] = f;
  }
}

// ---------------- kernel 3: Clenshaw-Curtis reduction -> z, jac ----------------
__global__ void reduce_kernel(const float* __restrict__ x, const float* __restrict__ h,
                              const float* __restrict__ fbuf, float* __restrict__ out) {
  __shared__ float ccw[NS];
  int tid = threadIdx.x;
  if (tid < NS) {
    double acc = 0.0;
#pragma unroll
    for (int i = 0; i <= 20; i += 2) {
      double wi = (i == 0) ? 1.0 : 2.0 / (1.0 - (double)(i * i));
      acc += cos((double)(i * tid) * 3.141592653589793 / 20.0) * wi;
    }
    double edge = (tid == 0 || tid == 20) ? 0.5 : 1.0;
    ccw[tid] = (float)(acc * 0.1 * edge);          // * 2/nb_steps * edge
  }
  __syncthreads();
  int t = blockIdx.x * blockDim.x + tid;
  if (t >= NBD) return;
  const float* fb = fbuf + t * NS;
  float acc = 0.f;
#pragma unroll
  for (int i = 0; i < NS; ++i) acc += fb[i] * ccw[i];
  float z = acc * x[t] * 0.5f + h[t * NCOND];
  out[t] = z;                     // z_est + h[:,:,0]
  out[NBD + t] = fb[0];           // jac = f at node s=0 (steps[0]==1 -> input == [x,h])
}

// ---------------- launcher ----------------
extern "C" void kernel_launch(void* const* d_in, const int* in_sizes, int n_in,
                              void* d_out, int out_size, void* d_ws, size_t ws_size,
                              hipStream_t stream) {
  (void)in_sizes; (void)n_in; (void)out_size; (void)ws_size;
  const float* x  = (const float*)d_in[0];
  const float* h  = (const float*)d_in[1];
  const float* W0 = (const float*)d_in[2];
  const float* b0 = (const float*)d_in[3];
  const float* W1 = (const float*)d_in[4];
  const float* b1 = (const float*)d_in[5];
  const float* W2 = (const float*)d_in[6];
  const float* b2 = (const float*)d_in[7];
  const float* W3 = (const float*)d_in[8];
  const float* b3 = (const float*)d_in[9];

  unsigned short* wp = (unsigned short*)d_ws;
  float* fbuf = (float*)((char*)d_ws + WP_TOTAL * sizeof(unsigned short));
  float* out  = (float*)d_out;

  prep_pack<<<(WP_TOTAL / 8 + 255) / 256, 256, 0, stream>>>(W0, W1, W2, wp);
  mlp_kernel<<<NBLOCKS, 256, 0, stream>>>(x, h, b0, b1, b2, W3, b3, wp, fbuf);
  reduce_kernel<<<(NBD + 255) / 256, 256, 0, stream>>>(x, h, fbuf, out);
}

// Round 2
// 170.944 us; speedup vs baseline: 1.4272x; 1.4272x over previous
//
#include <hip/hip_runtime.h>
#include <math.h>

// ---------------- problem constants ----------------
#define NB        512
#define ND        32
#define NCOND     30
#define NS        21                  // NB_STEPS+1 quadrature nodes
#define NBD       (NB*ND)             // 16384
#define NROWS     (NBD*NS)            // 344064 MLP evaluations
#define MBLK      128                 // rows per block
#define NBLOCKS   (NROWS/MBLK)        // 2688

// packed-weight element counts (ushort): W0 1 ktile, W1/W2 8 ktiles, 16 coltiles
#define W0P_ELEMS (1*16*64*8)         // 8192
#define W1P_ELEMS (8*16*64*8)         // 65536
#define WP_TOTAL  (W0P_ELEMS + 2*W1P_ELEMS)  // 139264

typedef __bf16 bf8 __attribute__((ext_vector_type(8)));
typedef float  fx4 __attribute__((ext_vector_type(4)));
typedef unsigned short us8 __attribute__((ext_vector_type(8)));

__device__ __forceinline__ unsigned short f2bf(float f) {
  unsigned int u = __float_as_uint(f);
  u += 0x7FFFu + ((u >> 16) & 1u);        // round-to-nearest-even
  return (unsigned short)(u >> 16);
}
__device__ __forceinline__ float bf2f(unsigned short b) {
  return __uint_as_float(((unsigned int)b) << 16);
}

// ---------------- kernel 1: pack weights to bf16 MFMA B-fragment order ----------
// packed index p = ((kt*16+ct)*64+lane)*8 + i ; source W[k][j], k=kt*32+(lane>>4)*8+i,
// j = ct*16 + (lane&15). K padded with zeros (W0: 31->32).
__global__ void prep_pack(const float* __restrict__ W0,
                          const float* __restrict__ W1,
                          const float* __restrict__ W2,
                          unsigned short* __restrict__ wp) {
  int t = blockIdx.x * blockDim.x + threadIdx.x;   // one thread = one 8-elem frag
  if (t >= WP_TOTAL / 8) return;
  int base = t * 8;
  const float* W;
  int rem, K;
  if (base < W0P_ELEMS)                      { W = W0; rem = base;                 K = 31;  }
  else if (base < W0P_ELEMS + W1P_ELEMS)     { W = W1; rem = base - W0P_ELEMS;     K = 256; }
  else                                       { W = W2; rem = base - W0P_ELEMS - W1P_ELEMS; K = 256; }
  int lane = (rem >> 3) & 63;
  int ct   = (rem >> 9) & 15;
  int ktl  =  rem >> 13;
  int j  = ct * 16 + (lane & 15);
  int k0 = ktl * 32 + (lane >> 4) * 8;
  us8 out;
#pragma unroll
  for (int i = 0; i < 8; ++i) {
    int k = k0 + i;
    float v = (k < K) ? W[k * 256 + j] : 0.0f;
    out[i] = f2bf(v);
  }
  *reinterpret_cast<us8*>(wp + base) = out;
}

// ---------------- fused MLP kernel ----------------
// 8 waves/block = 512 threads. Block = 128 rows. Wave w owns cols [w*32, w*32+32)
// (2 col-tiles) and ALL 128 rows (8 row-tiles) -> B-fragment reuse x8.
// Activations [128][256] bf16 ping-pong between ldsA/ldsB (64 KB each),
// byte-swizzle off ^= (row&7)<<4 for conflict-light ds_read_b128.

__device__ __forceinline__ bf8 lds_afrag(const unsigned char* src, int lane, int rt, int kt) {
  int row = rt * 16 + (lane & 15);
  unsigned int off = (unsigned int)(row * 512 + kt * 64 + (lane >> 4) * 16);
  off ^= (unsigned int)((row & 7) << 4);
  return *reinterpret_cast<const bf8*>(src + off);
}

// store one wave's [128 x 32] C-slab with bias+ReLU to bf16 LDS
__device__ __forceinline__ void act_store(unsigned char* dst, int wv, int lane,
                                          const fx4 acc[8][2], const float* __restrict__ bias) {
  int colb  = lane & 15;
  int khalf = lane >> 4;
#pragma unroll
  for (int ct = 0; ct < 2; ++ct) {
    int col = wv * 32 + ct * 16 + colb;
    float bv = bias[col];
#pragma unroll
    for (int rt = 0; rt < 8; ++rt) {
#pragma unroll
      for (int reg = 0; reg < 4; ++reg) {
        int row = rt * 16 + khalf * 4 + reg;         // C layout: row=(lane>>4)*4+reg
        float v = fmaxf(acc[rt][ct][reg] + bv, 0.0f);  // ReLU
        unsigned int off = (unsigned int)(row * 512 + col * 2);
        off ^= (unsigned int)((row & 7) << 4);
        *reinterpret_cast<unsigned short*>(dst + off) = f2bf(v);
      }
    }
  }
}

__global__ __launch_bounds__(512, 2)
void mlp_kernel(const float* __restrict__ x, const float* __restrict__ h,
                const float* __restrict__ b0, const float* __restrict__ b1,
                const float* __restrict__ b2, const float* __restrict__ W3,
                const float* __restrict__ b3,
                const unsigned short* __restrict__ wp,
                float* __restrict__ fbuf) {
  __shared__ __align__(16) unsigned char ldsA[128 * 512];
  __shared__ __align__(16) unsigned char ldsB[128 * 512];   // 128 KiB total

  int tid  = threadIdx.x;
  int wv   = tid >> 6;
  int lane = tid & 63;
  int R0   = blockIdx.x * MBLK;

  // ---- stage layer-0 input [128 rows][32 bf16] into ldsB (first 8 KB) ----
  {
    int r = tid >> 2;                   // 0..127
    int q = tid & 3;                    // 8-col chunk
    int gr = R0 + r;
    unsigned int bd = (unsigned int)gr / NS;
    int s = gr - (int)bd * NS;
    float xv = x[bd];
    float node = xv * (cosf((float)s * 0.15707963267948966f) + 1.0f) * 0.5f;
    const float* hrow = h + bd * NCOND;
    us8 au;
#pragma unroll
    for (int i = 0; i < 8; ++i) {
      int c = q * 8 + i;
      float v;
      if (c == 0)       v = node;
      else if (c <= 30) v = hrow[c - 1];
      else              v = 0.0f;
      au[i] = f2bf(v);
    }
    unsigned int off = (unsigned int)(r * 64 + q * 16) ^ (unsigned int)((r & 3) << 4);
    *reinterpret_cast<us8*>(ldsB + off) = au;
  }
  __syncthreads();

  fx4 acc[8][2];

  // ---- layer 0: K=32 (one MFMA K-step) ----
  {
#pragma unroll
    for (int rt = 0; rt < 8; ++rt)
#pragma unroll
      for (int ct = 0; ct < 2; ++ct) acc[rt][ct] = fx4{0.f, 0.f, 0.f, 0.f};
    bf8 bfr[2];
#pragma unroll
    for (int ct = 0; ct < 2; ++ct) {
      int ctg = wv * 2 + ct;
      bfr[ct] = *reinterpret_cast<const bf8*>(wp + (ctg * 64 + lane) * 8);
    }
#pragma unroll
    for (int rt = 0; rt < 8; ++rt) {
      int row = rt * 16 + (lane & 15);
      unsigned int off = (unsigned int)(row * 64 + (lane >> 4) * 16)
                       ^ (unsigned int)((row & 3) << 4);
      bf8 a = *reinterpret_cast<const bf8*>(ldsB + off);
#pragma unroll
      for (int ct = 0; ct < 2; ++ct)
        acc[rt][ct] = __builtin_amdgcn_mfma_f32_16x16x32_bf16(a, bfr[ct], acc[rt][ct], 0, 0, 0);
    }
    __syncthreads();           // ensure all layer-0 input reads done before store phase races? (store goes to ldsA; barrier below suffices) -- kept for clean ordering of ldsB reuse
    act_store(ldsA, wv, lane, acc, b0);
  }
  __syncthreads();

  const unsigned short* wb1 = wp + W0P_ELEMS;
  const unsigned short* wb2 = wp + W0P_ELEMS + W1P_ELEMS;

  // ---- layer 1: 256->256, 8 K-steps, read ldsA, write ldsB ----
  {
#pragma unroll
    for (int rt = 0; rt < 8; ++rt)
#pragma unroll
      for (int ct = 0; ct < 2; ++ct) acc[rt][ct] = fx4{0.f, 0.f, 0.f, 0.f};
#pragma unroll
    for (int kt = 0; kt < 8; ++kt) {
      bf8 bfr[2];
#pragma unroll
      for (int ct = 0; ct < 2; ++ct) {
        int ctg = wv * 2 + ct;
        bfr[ct] = *reinterpret_cast<const bf8*>(wb1 + ((kt * 16 + ctg) * 64 + lane) * 8);
      }
#pragma unroll
      for (int rt = 0; rt < 8; ++rt) {
        bf8 a = lds_afrag(ldsA, lane, rt, kt);
#pragma unroll
        for (int ct = 0; ct < 2; ++ct)
          acc[rt][ct] = __builtin_amdgcn_mfma_f32_16x16x32_bf16(a, bfr[ct], acc[rt][ct], 0, 0, 0);
      }
    }
    act_store(ldsB, wv, lane, acc, b1);
  }
  __syncthreads();

  // ---- layer 2: read ldsB, write ldsA ----
  {
#pragma unroll
    for (int rt = 0; rt < 8; ++rt)
#pragma unroll
      for (int ct = 0; ct < 2; ++ct) acc[rt][ct] = fx4{0.f, 0.f, 0.f, 0.f};
#pragma unroll
    for (int kt = 0; kt < 8; ++kt) {
      bf8 bfr[2];
#pragma unroll
      for (int ct = 0; ct < 2; ++ct) {
        int ctg = wv * 2 + ct;
        bfr[ct] = *reinterpret_cast<const bf8*>(wb2 + ((kt * 16 + ctg) * 64 + lane) * 8);
      }
#pragma unroll
      for (int rt = 0; rt < 8; ++rt) {
        bf8 a = lds_afrag(ldsB, lane, rt, kt);
#pragma unroll
        for (int ct = 0; ct < 2; ++ct)
          acc[rt][ct] = __builtin_amdgcn_mfma_f32_16x16x32_bf16(a, bfr[ct], acc[rt][ct], 0, 0, 0);
      }
    }
    act_store(ldsA, wv, lane, acc, b2);
  }
  __syncthreads();

  // ---- layer 3: 256 -> 1 dot product (VALU), ELU(y)+1 ----
  {
    int row = tid >> 2;           // 0..127
    int sub = tid & 3;            // 4 lanes share a row, 64 cols each
    float sum = 0.f;
#pragma unroll
    for (int jj = 0; jj < 8; ++jj) {
      int cbase = sub * 64 + jj * 8;
      unsigned int off = (unsigned int)(row * 512 + cbase * 2);
      off ^= (unsigned int)((row & 7) << 4);
      us8 av = *reinterpret_cast<const us8*>(ldsA + off);
#pragma unroll
      for (int ii = 0; ii < 8; ++ii)
        sum += bf2f(av[ii]) * W3[cbase + ii];
    }
    sum += __shfl_down(sum, 2);
    sum += __shfl_down(sum, 1);
    if (sub == 0) {
      float y = sum + b3[0];
      float f = (y > 0.f) ? (y + 1.f) : expf(y);   // elu(y)+1
      fbuf[R0 + row] = f;
    }
  }
}

// ---------------- kernel 3: Clenshaw-Curtis reduction -> z, jac ----------------
__global__ void reduce_kernel(const float* __restrict__ x, const float* __restrict__ h,
                              const float* __restrict__ fbuf, float* __restrict__ out) {
  __shared__ float ccw[NS];
  int tid = threadIdx.x;
  if (tid < NS) {
    double acc = 0.0;
#pragma unroll
    for (int i = 0; i <= 20; i += 2) {
      double wi = (i == 0) ? 1.0 : 2.0 / (1.0 - (double)(i * i));
      acc += cos((double)(i * tid) * 3.141592653589793 / 20.0) * wi;
    }
    double edge = (tid == 0 || tid == 20) ? 0.5 : 1.0;
    ccw[tid] = (float)(acc * 0.1 * edge);          // * 2/nb_steps * edge
  }
  __syncthreads();
  int t = blockIdx.x * blockDim.x + tid;
  if (t >= NBD) return;
  const float* fb = fbuf + t * NS;
  float acc = 0.f;
#pragma unroll
  for (int i = 0; i < NS; ++i) acc += fb[i] * ccw[i];
  float z = acc * x[t] * 0.5f + h[t * NCOND];
  out[t] = z;                     // z_est + h[:,:,0]
  out[NBD + t] = fb[0];           // jac = f at node s=0 (steps[0]==1 -> input == [x,h])
}

// ---------------- launcher ----------------
extern "C" void kernel_launch(void* const* d_in, const int* in_sizes, int n_in,
                              void* d_out, int out_size, void* d_ws, size_t ws_size,
                              hipStream_t stream) {
  (void)in_sizes; (void)n_in; (void)out_size; (void)ws_size;
  const float* x  = (const float*)d_in[0];
  const float* h  = (const float*)d_in[1];
  const float* W0 = (const float*)d_in[2];
  const float* b0 = (const float*)d_in[3];
  const float* W1 = (const float*)d_in[4];
  const float* b1 = (const float*)d_in[5];
  const float* W2 = (const float*)d_in[6];
  const float* b2 = (const float*)d_in[7];
  const float* W3 = (const float*)d_in[8];
  const float* b3 = (const float*)d_in[9];

  unsigned short* wp = (unsigned short*)d_ws;
  float* fbuf = (float*)((char*)d_ws + WP_TOTAL * sizeof(unsigned short));
  float* out  = (float*)d_out;

  prep_pack<<<(WP_TOTAL / 8 + 255) / 256, 256, 0, stream>>>(W0, W1, W2, wp);
  mlp_kernel<<<NBLOCKS, 512, 0, stream>>>(x, h, b0, b1, b2, W3, b3, wp, fbuf);
  reduce_kernel<<<(NBD + 255) / 256, 256, 0, stream>>>(x, h, fbuf, out);
}

// Round 3
// 127.577 us; speedup vs baseline: 1.9123x; 1.3399x over previous
//
#include <hip/hip_runtime.h>
#include <math.h>

// ---------------- problem constants ----------------
#define NB        512
#define ND        32
#define NCOND     30
#define NS        21                  // NB_STEPS+1 quadrature nodes
#define NBD       (NB*ND)             // 16384
#define NROWS     (NBD*NS)            // 344064 MLP evaluations
#define MBLK      64                  // rows per block
#define NBLOCKS   (NROWS/MBLK)        // 5376

// packed-weight element counts (ushort)
#define W0P_ELEMS (1*16*64*8)         // 8192
#define W1P_ELEMS (8*16*64*8)         // 65536
#define W3P_ELEMS (8*64*8)            // 4096  (zero-padded W3 as A-fragments)
#define WP_TOTAL  (W0P_ELEMS + 2*W1P_ELEMS + W3P_ELEMS)  // 143360

typedef __bf16 bf8 __attribute__((ext_vector_type(8)));
typedef float  fx4 __attribute__((ext_vector_type(4)));
typedef unsigned short us8 __attribute__((ext_vector_type(8)));

__device__ __forceinline__ unsigned short f2bf(float f) {
  unsigned int u = __float_as_uint(f);
  u += 0x7FFFu + ((u >> 16) & 1u);        // round-to-nearest-even
  return (unsigned short)(u >> 16);
}

// ---------------- kernel 1: pack weights to bf16 MFMA fragment order ----------
// Fragment layout (serves BOTH as B-frag of W and A-frag of W^T):
//   p = ((kt*16+ct)*64+lane)*8 + i  holds W[kt*32+(lane>>4)*8+i][ct*16+(lane&15)]
// W3 region: A-frag of W3^T zero-padded to 16 rows (only row 0 nonzero).
__global__ void prep_pack(const float* __restrict__ W0,
                          const float* __restrict__ W1,
                          const float* __restrict__ W2,
                          const float* __restrict__ W3,
                          unsigned short* __restrict__ wp) {
  int t = blockIdx.x * blockDim.x + threadIdx.x;   // one thread = one 8-elem frag
  if (t >= WP_TOTAL / 8) return;
  int base = t * 8;
  us8 out;
  if (base >= W0P_ELEMS + 2 * W1P_ELEMS) {         // W3 region
    int rem  = base - (W0P_ELEMS + 2 * W1P_ELEMS);
    int lane = (rem >> 3) & 63;
    int ktl  = rem >> 9;
    int k0   = ktl * 32 + (lane >> 4) * 8;
#pragma unroll
    for (int i = 0; i < 8; ++i)
      out[i] = ((lane & 15) == 0) ? f2bf(W3[k0 + i]) : (unsigned short)0;
  } else {
    const float* W; int rem, K;
    if (base < W0P_ELEMS)                  { W = W0; rem = base;                 K = 31;  }
    else if (base < W0P_ELEMS + W1P_ELEMS) { W = W1; rem = base - W0P_ELEMS;     K = 256; }
    else                                   { W = W2; rem = base - W0P_ELEMS - W1P_ELEMS; K = 256; }
    int lane = (rem >> 3) & 63;
    int ct   = (rem >> 9) & 15;
    int ktl  =  rem >> 13;
    int j  = ct * 16 + (lane & 15);
    int k0 = ktl * 32 + (lane >> 4) * 8;
#pragma unroll
    for (int i = 0; i < 8; ++i) {
      int k = k0 + i;
      out[i] = (k < K) ? f2bf(W[k * 256 + j]) : (unsigned short)0;
    }
  }
  *reinterpret_cast<us8*>(wp + base) = out;
}

// ---------------- fused MLP kernel ----------------
// 8 waves = 2 row-groups x 4 col-groups. Block = 64 rows. Wave owns 32 rows
// (2 row-tiles) x 64 neurons (4 col-tiles). Swapped MFMA: D = mfma(W^T, act^T)
// -> lane holds act-row m = rt*16+(lane&15), neurons n = ct*16+(lane>>4)*4+reg
// (4 consecutive -> packed ds_write_b64). Swizzle ^((m&15)<<4): conflict-free.

__global__ __launch_bounds__(512, 4)
void mlp_kernel(const float* __restrict__ x, const float* __restrict__ h,
                const float* __restrict__ b0, const float* __restrict__ b1,
                const float* __restrict__ b2, const float* __restrict__ b3,
                const unsigned short* __restrict__ wp,
                float* __restrict__ fbuf) {
  __shared__ __align__(16) unsigned char ldsA[64 * 512];
  __shared__ __align__(16) unsigned char ldsB[64 * 512];   // 64 KiB total

  int tid  = threadIdx.x;
  int wv   = tid >> 6;
  int lane = tid & 63;
  int rgrp = wv >> 2;            // 0..1 : row half
  int cgrp = wv & 3;             // 0..3 : 64-neuron group
  int colb  = lane & 15;
  int khalf = lane >> 4;
  int R0 = blockIdx.x * MBLK;

  // ---- stage layer-0 input [64 rows][32 bf16] into ldsB (first 4 KB) ----
  if (tid < 256) {
    int r = tid >> 2;                   // 0..63
    int q = tid & 3;                    // 8-col chunk
    int gr = R0 + r;
    unsigned int bd = (unsigned int)gr / NS;
    int s = gr - (int)bd * NS;
    float xv = x[bd];
    float node = xv * (cosf((float)s * 0.15707963267948966f) + 1.0f) * 0.5f;
    const float* hrow = h + bd * NCOND;
    us8 au;
#pragma unroll
    for (int i = 0; i < 8; ++i) {
      int c = q * 8 + i;
      float v;
      if (c == 0)       v = node;
      else if (c <= 30) v = hrow[c - 1];
      else              v = 0.0f;
      au[i] = f2bf(v);
    }
    unsigned int off = (unsigned int)(r * 64 + q * 16) ^ (unsigned int)((r & 3) << 4);
    *reinterpret_cast<us8*>(ldsB + off) = au;
  }
  __syncthreads();

  fx4 acc[2][4];

  // ======== layer 0: K=32 (one K-step), read ldsB input, store ldsA ========
  {
#pragma unroll
    for (int rt = 0; rt < 2; ++rt)
#pragma unroll
      for (int ct = 0; ct < 4; ++ct) acc[rt][ct] = fx4{0.f, 0.f, 0.f, 0.f};
    bf8 w[4];
#pragma unroll
    for (int ct = 0; ct < 4; ++ct)
      w[ct] = *reinterpret_cast<const bf8*>(wp + ((cgrp * 4 + ct) * 64 + lane) * 8);
#pragma unroll
    for (int rt = 0; rt < 2; ++rt) {
      int m = rgrp * 32 + rt * 16 + colb;
      unsigned int off = (unsigned int)(m * 64 + khalf * 16) ^ (unsigned int)((m & 3) << 4);
      bf8 a = *reinterpret_cast<const bf8*>(ldsB + off);
#pragma unroll
      for (int ct = 0; ct < 4; ++ct)
        acc[rt][ct] = __builtin_amdgcn_mfma_f32_16x16x32_bf16(w[ct], a, acc[rt][ct], 0, 0, 0);
    }
  }
  // act_store -> ldsA (bias b0 + ReLU)
  {
    float4 bv[4];
#pragma unroll
    for (int ct = 0; ct < 4; ++ct)
      bv[ct] = *reinterpret_cast<const float4*>(b0 + (cgrp * 4 + ct) * 16 + khalf * 4);
#pragma unroll
    for (int rt = 0; rt < 2; ++rt) {
      int m = rgrp * 32 + rt * 16 + colb;
      unsigned int base = (unsigned int)(m * 512);
      unsigned int swz  = (unsigned int)((m & 15) << 4);
#pragma unroll
      for (int ct = 0; ct < 4; ++ct) {
        int n0 = (cgrp * 4 + ct) * 16 + khalf * 4;
        float v0 = fmaxf(acc[rt][ct][0] + bv[ct].x, 0.f);
        float v1 = fmaxf(acc[rt][ct][1] + bv[ct].y, 0.f);
        float v2 = fmaxf(acc[rt][ct][2] + bv[ct].z, 0.f);
        float v3 = fmaxf(acc[rt][ct][3] + bv[ct].w, 0.f);
        unsigned int p0, p1;
        asm("v_cvt_pk_bf16_f32 %0, %1, %2" : "=v"(p0) : "v"(v0), "v"(v1));
        asm("v_cvt_pk_bf16_f32 %0, %1, %2" : "=v"(p1) : "v"(v2), "v"(v3));
        uint2 pk; pk.x = p0; pk.y = p1;
        *reinterpret_cast<uint2*>(ldsA + ((base + (unsigned int)(n0 * 2)) ^ swz)) = pk;
      }
    }
  }
  __syncthreads();

  const unsigned short* wb1 = wp + W0P_ELEMS;
  const unsigned short* wb2 = wp + W0P_ELEMS + W1P_ELEMS;
  const unsigned short* w3p = wp + W0P_ELEMS + 2 * W1P_ELEMS;

  // ======== layer 1: read ldsA, store ldsB ========
  {
#pragma unroll
    for (int rt = 0; rt < 2; ++rt)
#pragma unroll
      for (int ct = 0; ct < 4; ++ct) acc[rt][ct] = fx4{0.f, 0.f, 0.f, 0.f};
#pragma unroll
    for (int kt = 0; kt < 8; ++kt) {
      bf8 w[4];
#pragma unroll
      for (int ct = 0; ct < 4; ++ct)
        w[ct] = *reinterpret_cast<const bf8*>(wb1 + ((kt * 16 + cgrp * 4 + ct) * 64 + lane) * 8);
#pragma unroll
      for (int rt = 0; rt < 2; ++rt) {
        int m = rgrp * 32 + rt * 16 + colb;
        unsigned int off = ((unsigned int)(m * 512 + kt * 64 + khalf * 16))
                         ^ ((unsigned int)((m & 15) << 4));
        bf8 a = *reinterpret_cast<const bf8*>(ldsA + off);
#pragma unroll
        for (int ct = 0; ct < 4; ++ct)
          acc[rt][ct] = __builtin_amdgcn_mfma_f32_16x16x32_bf16(w[ct], a, acc[rt][ct], 0, 0, 0);
      }
    }
    float4 bv[4];
#pragma unroll
    for (int ct = 0; ct < 4; ++ct)
      bv[ct] = *reinterpret_cast<const float4*>(b1 + (cgrp * 4 + ct) * 16 + khalf * 4);
#pragma unroll
    for (int rt = 0; rt < 2; ++rt) {
      int m = rgrp * 32 + rt * 16 + colb;
      unsigned int base = (unsigned int)(m * 512);
      unsigned int swz  = (unsigned int)((m & 15) << 4);
#pragma unroll
      for (int ct = 0; ct < 4; ++ct) {
        int n0 = (cgrp * 4 + ct) * 16 + khalf * 4;
        float v0 = fmaxf(acc[rt][ct][0] + bv[ct].x, 0.f);
        float v1 = fmaxf(acc[rt][ct][1] + bv[ct].y, 0.f);
        float v2 = fmaxf(acc[rt][ct][2] + bv[ct].z, 0.f);
        float v3 = fmaxf(acc[rt][ct][3] + bv[ct].w, 0.f);
        unsigned int p0, p1;
        asm("v_cvt_pk_bf16_f32 %0, %1, %2" : "=v"(p0) : "v"(v0), "v"(v1));
        asm("v_cvt_pk_bf16_f32 %0, %1, %2" : "=v"(p1) : "v"(v2), "v"(v3));
        uint2 pk; pk.x = p0; pk.y = p1;
        *reinterpret_cast<uint2*>(ldsB + ((base + (unsigned int)(n0 * 2)) ^ swz)) = pk;
      }
    }
  }
  __syncthreads();

  // ======== layer 2: read ldsB, store ldsA ========
  {
#pragma unroll
    for (int rt = 0; rt < 2; ++rt)
#pragma unroll
      for (int ct = 0; ct < 4; ++ct) acc[rt][ct] = fx4{0.f, 0.f, 0.f, 0.f};
#pragma unroll
    for (int kt = 0; kt < 8; ++kt) {
      bf8 w[4];
#pragma unroll
      for (int ct = 0; ct < 4; ++ct)
        w[ct] = *reinterpret_cast<const bf8*>(wb2 + ((kt * 16 + cgrp * 4 + ct) * 64 + lane) * 8);
#pragma unroll
      for (int rt = 0; rt < 2; ++rt) {
        int m = rgrp * 32 + rt * 16 + colb;
        unsigned int off = ((unsigned int)(m * 512 + kt * 64 + khalf * 16))
                         ^ ((unsigned int)((m & 15) << 4));
        bf8 a = *reinterpret_cast<const bf8*>(ldsB + off);
#pragma unroll
        for (int ct = 0; ct < 4; ++ct)
          acc[rt][ct] = __builtin_amdgcn_mfma_f32_16x16x32_bf16(w[ct], a, acc[rt][ct], 0, 0, 0);
      }
    }
    float4 bv[4];
#pragma unroll
    for (int ct = 0; ct < 4; ++ct)
      bv[ct] = *reinterpret_cast<const float4*>(b2 + (cgrp * 4 + ct) * 16 + khalf * 4);
#pragma unroll
    for (int rt = 0; rt < 2; ++rt) {
      int m = rgrp * 32 + rt * 16 + colb;
      unsigned int base = (unsigned int)(m * 512);
      unsigned int swz  = (unsigned int)((m & 15) << 4);
#pragma unroll
      for (int ct = 0; ct < 4; ++ct) {
        int n0 = (cgrp * 4 + ct) * 16 + khalf * 4;
        float v0 = fmaxf(acc[rt][ct][0] + bv[ct].x, 0.f);
        float v1 = fmaxf(acc[rt][ct][1] + bv[ct].y, 0.f);
        float v2 = fmaxf(acc[rt][ct][2] + bv[ct].z, 0.f);
        float v3 = fmaxf(acc[rt][ct][3] + bv[ct].w, 0.f);
        unsigned int p0, p1;
        asm("v_cvt_pk_bf16_f32 %0, %1, %2" : "=v"(p0) : "v"(v0), "v"(v1));
        asm("v_cvt_pk_bf16_f32 %0, %1, %2" : "=v"(p1) : "v"(v2), "v"(v3));
        uint2 pk; pk.x = p0; pk.y = p1;
        *reinterpret_cast<uint2*>(ldsA + ((base + (unsigned int)(n0 * 2)) ^ swz)) = pk;
      }
    }
  }
  __syncthreads();

  // ======== layer 3: 256 -> 1 via MFMA with zero-padded W3^T (cgrp 0 only) ====
  if (cgrp == 0) {
    fx4 a3[2];
    a3[0] = fx4{0.f, 0.f, 0.f, 0.f};
    a3[1] = fx4{0.f, 0.f, 0.f, 0.f};
#pragma unroll
    for (int kt = 0; kt < 8; ++kt) {
      bf8 w3f = *reinterpret_cast<const bf8*>(w3p + (kt * 64 + lane) * 8);
#pragma unroll
      for (int rt = 0; rt < 2; ++rt) {
        int m = rgrp * 32 + rt * 16 + colb;
        unsigned int off = ((unsigned int)(m * 512 + kt * 64 + khalf * 16))
                         ^ ((unsigned int)((m & 15) << 4));
        bf8 a = *reinterpret_cast<const bf8*>(ldsA + off);
        a3[rt] = __builtin_amdgcn_mfma_f32_16x16x32_bf16(w3f, a, a3[rt], 0, 0, 0);
      }
    }
    if (lane < 16) {
      float bias3 = b3[0];
#pragma unroll
      for (int rt = 0; rt < 2; ++rt) {
        float y = a3[rt][0] + bias3;
        float f = (y > 0.f) ? (y + 1.f) : expf(y);   // elu(y)+1
        fbuf[R0 + rgrp * 32 + rt * 16 + lane] = f;
      }
    }
  }
}

// ---------------- kernel 3: Clenshaw-Curtis reduction -> z, jac ----------------
__global__ void reduce_kernel(const float* __restrict__ x, const float* __restrict__ h,
                              const float* __restrict__ fbuf, float* __restrict__ out) {
  __shared__ float ccw[NS];
  int tid = threadIdx.x;
  if (tid < NS) {
    double acc = 0.0;
#pragma unroll
    for (int i = 0; i <= 20; i += 2) {
      double wi = (i == 0) ? 1.0 : 2.0 / (1.0 - (double)(i * i));
      acc += cos((double)(i * tid) * 3.141592653589793 / 20.0) * wi;
    }
    double edge = (tid == 0 || tid == 20) ? 0.5 : 1.0;
    ccw[tid] = (float)(acc * 0.1 * edge);          // * 2/nb_steps * edge
  }
  __syncthreads();
  int t = blockIdx.x * blockDim.x + tid;
  if (t >= NBD) return;
  const float* fb = fbuf + t * NS;
  float acc = 0.f;
#pragma unroll
  for (int i = 0; i < NS; ++i) acc += fb[i] * ccw[i];
  float z = acc * x[t] * 0.5f + h[t * NCOND];
  out[t] = z;                     // z_est + h[:,:,0]
  out[NBD + t] = fb[0];           // jac = f at node s=0 (steps[0]==1 -> input == [x,h])
}

// ---------------- launcher ----------------
extern "C" void kernel_launch(void* const* d_in, const int* in_sizes, int n_in,
                              void* d_out, int out_size, void* d_ws, size_t ws_size,
                              hipStream_t stream) {
  (void)in_sizes; (void)n_in; (void)out_size; (void)ws_size;
  const float* x  = (const float*)d_in[0];
  const float* h  = (const float*)d_in[1];
  const float* W0 = (const float*)d_in[2];
  const float* b0 = (const float*)d_in[3];
  const float* W1 = (const float*)d_in[4];
  const float* b1 = (const float*)d_in[5];
  const float* W2 = (const float*)d_in[6];
  const float* b2 = (const float*)d_in[7];
  const float* W3 = (const float*)d_in[8];
  const float* b3 = (const float*)d_in[9];

  unsigned short* wp = (unsigned short*)d_ws;
  float* fbuf = (float*)((char*)d_ws + WP_TOTAL * sizeof(unsigned short));
  float* out  = (float*)d_out;

  prep_pack<<<(WP_TOTAL / 8 + 255) / 256, 256, 0, stream>>>(W0, W1, W2, W3, wp);
  mlp_kernel<<<NBLOCKS, 512, 0, stream>>>(x, h, b0, b1, b2, b3, wp, fbuf);
  reduce_kernel<<<(NBD + 255) / 256, 256, 0, stream>>>(x, h, fbuf, out);
}